// Round 6
// baseline (123.359 us; speedup 1.0000x reference)
//
#include <hip/hip_runtime.h>

typedef __bf16 bf16;
typedef __bf16 bf16x4 __attribute__((ext_vector_type(4)));
typedef __bf16 bf16x8 __attribute__((ext_vector_type(8)));
typedef float  f32x4  __attribute__((ext_vector_type(4)));

#define MFMA16(a, b, c) __builtin_amdgcn_mfma_f32_16x16x32_bf16((a), (b), (c), 0, 0, 0)

static constexpr int Bn = 8, T = 2048, C = 1024, H = 128;
static constexpr int M = Bn * T; // 16384

// ---------------------------------------------------------------------------
// Kernel 0: transpose + hi/lo split  W[C][H] fp32 -> wt_hi/wt_lo [3][H][C] bf16
// ---------------------------------------------------------------------------
__global__ __launch_bounds__(256) void kwt(const float* __restrict__ Wq,
                                           const float* __restrict__ Wk,
                                           const float* __restrict__ Wv,
                                           bf16* __restrict__ wth,
                                           bf16* __restrict__ wtl) {
  __shared__ float tl[32][33];
  const int w = blockIdx.z;
  const float* src = (w == 0) ? Wq : (w == 1) ? Wk : Wv;
  bf16* dh = wth + (size_t)w * H * C;
  bf16* dl = wtl + (size_t)w * H * C;
  const int k0 = blockIdx.x * 32, n0 = blockIdx.y * 32;
  const int tx = threadIdx.x & 31, ty = threadIdx.x >> 5; // 32 x 8
  for (int i = ty; i < 32; i += 8) tl[i][tx] = src[(size_t)(k0 + i) * H + n0 + tx];
  __syncthreads();
  for (int i = ty; i < 32; i += 8) {
    float v = tl[tx][i];
    bf16 h = (bf16)v;
    bf16 l = (bf16)(v - (float)h);
    dh[(size_t)(n0 + i) * C + k0 + tx] = h;
    dl[(size_t)(n0 + i) * C + k0 + tx] = l;
  }
}

// ---------------------------------------------------------------------------
// Kernel 1: QKV projection, split-bf16 3-term (hh + lh + hl) for q,k accuracy;
// V (which==2) uses hh only (rounded to bf16 anyway).
// grid (M/64, 3).  256 thr = 4 waves (2x2).  Tile 64m x 128n, BK=64.
// ---------------------------------------------------------------------------
__global__ __launch_bounds__(256) void proj_kernel(const float* __restrict__ x,
                                                   const bf16* __restrict__ wth,
                                                   const bf16* __restrict__ wtl,
                                                   bf16* __restrict__ qh, bf16* __restrict__ ql,
                                                   bf16* __restrict__ kh, bf16* __restrict__ kl,
                                                   bf16* __restrict__ vt) {
  __shared__ __align__(16) bf16 Ah[64 * 72], Al[64 * 72];    // [m][k] padded
  __shared__ __align__(16) bf16 Bh[128 * 72], Bl[128 * 72];  // [n][k] padded
  const int tid = threadIdx.x;
  const int lane = tid & 63, g = lane >> 4, r16 = lane & 15;
  const int wave = tid >> 6, wr = wave >> 1, wc = wave & 1;
  const int m0 = blockIdx.x * 64;
  const int which = blockIdx.y;
  const bool split = (which < 2);
  const bf16* wh = wth + (size_t)which * H * C;
  const bf16* wl = wtl + (size_t)which * H * C;

  int am[4], ak[4], bn[4], bk[4];
#pragma unroll
  for (int it = 0; it < 4; ++it) {
    int c = it * 256 + tid;
    am[it] = c >> 4; ak[it] = (c & 15) << 2;
    bn[it] = c >> 3; bk[it] = (c & 7) << 3;
  }

  f32x4 ra[4]; bf16x8 rbh[4], rbl[4];
#pragma unroll
  for (int it = 0; it < 4; ++it) {
    ra[it]  = *(const f32x4*)&x[(size_t)(m0 + am[it]) * C + ak[it]];
    rbh[it] = *(const bf16x8*)&wh[(size_t)bn[it] * C + bk[it]];
    if (split) rbl[it] = *(const bf16x8*)&wl[(size_t)bn[it] * C + bk[it]];
  }

  f32x4 acc[2][4] = {};

  for (int k0 = 0; k0 < C; k0 += 64) {
    __syncthreads();
#pragma unroll
    for (int it = 0; it < 4; ++it) {
      bf16x4 hv, lv;
#pragma unroll
      for (int j = 0; j < 4; ++j) {
        float v = ra[it][j];
        bf16 h = (bf16)v;
        hv[j] = h;
        lv[j] = (bf16)(v - (float)h);
      }
      *(bf16x4*)&Ah[am[it] * 72 + ak[it]] = hv;
      *(bf16x8*)&Bh[bn[it] * 72 + bk[it]] = rbh[it];
      if (split) {
        *(bf16x4*)&Al[am[it] * 72 + ak[it]] = lv;
        *(bf16x8*)&Bl[bn[it] * 72 + bk[it]] = rbl[it];
      }
    }
    if (k0 + 64 < C) {
      const int kn = k0 + 64;
#pragma unroll
      for (int it = 0; it < 4; ++it) {
        ra[it]  = *(const f32x4*)&x[(size_t)(m0 + am[it]) * C + kn + ak[it]];
        rbh[it] = *(const bf16x8*)&wh[(size_t)bn[it] * C + kn + bk[it]];
        if (split) rbl[it] = *(const bf16x8*)&wl[(size_t)bn[it] * C + kn + bk[it]];
      }
    }
    __syncthreads();
#pragma unroll
    for (int kb = 0; kb < 2; ++kb) {
      bf16x8 afh[2], afl[2], bfh[4], bfl[4];
#pragma unroll
      for (int mt = 0; mt < 2; ++mt) {
        const int ro = (wr * 32 + mt * 16 + r16) * 72 + kb * 32 + g * 8;
        afh[mt] = *(const bf16x8*)&Ah[ro];
        if (split) afl[mt] = *(const bf16x8*)&Al[ro];
      }
#pragma unroll
      for (int nt = 0; nt < 4; ++nt) {
        const int ro = (wc * 64 + nt * 16 + r16) * 72 + kb * 32 + g * 8;
        bfh[nt] = *(const bf16x8*)&Bh[ro];
        if (split) bfl[nt] = *(const bf16x8*)&Bl[ro];
      }
#pragma unroll
      for (int mt = 0; mt < 2; ++mt)
#pragma unroll
        for (int nt = 0; nt < 4; ++nt) {
          acc[mt][nt] = MFMA16(afh[mt], bfh[nt], acc[mt][nt]);
          if (split) {
            acc[mt][nt] = MFMA16(afl[mt], bfh[nt], acc[mt][nt]);
            acc[mt][nt] = MFMA16(afh[mt], bfl[nt], acc[mt][nt]);
          }
        }
    }
  }

  if (which < 2) {
    bf16* dh = which ? kh : qh;
    bf16* dl = which ? kl : ql;
#pragma unroll
    for (int mt = 0; mt < 2; ++mt)
#pragma unroll
      for (int nt = 0; nt < 4; ++nt) {
        const int mb = m0 + wr * 32 + mt * 16 + g * 4;
        const int col = wc * 64 + nt * 16 + r16;
#pragma unroll
        for (int r = 0; r < 4; ++r) {
          float v = acc[mt][nt][r];
          bf16 h = (bf16)v;
          dh[(size_t)(mb + r) * H + col] = h;
          dl[(size_t)(mb + r) * H + col] = (bf16)(v - (float)h);
        }
      }
  } else {
    const int b = m0 >> 11;
    const int tb0 = m0 & 2047;
    bf16* vbase = vt + (size_t)b * H * T;
#pragma unroll
    for (int mt = 0; mt < 2; ++mt)
#pragma unroll
      for (int nt = 0; nt < 4; ++nt) {
        const int tib = tb0 + wr * 32 + mt * 16 + g * 4;
        const int h = wc * 64 + nt * 16 + r16;
        bf16x4 pk;
#pragma unroll
        for (int r = 0; r < 4; ++r) pk[r] = (bf16)acc[mt][nt][r];
        *(bf16x4*)&vbase[(size_t)h * T + tib] = pk;
      }
  }
}

// ---------------------------------------------------------------------------
// Kernel 2: causal flash attention, LDS-shared K/V tiles, s-parity split.
// 512 blocks: batch = bb&7 (XCD-pinned K/V), i = bb>>3, qt = i<32 ? 63-i : i-32
// (first 256 blocks heavy, next 256 light -> each CU gets ~const total work
// with 2 blocks/CU resident).  Block = 32 q-rows: waves 0,1 -> rows [0,16)
// at s-tile parity 0/1; waves 2,3 -> rows [16,32).  All 4 waves co-stage
// K hi/lo + V^T (58KB, XOR chunk-swizzled, reg-prefetch T14).  End: 2-way
// (m,l,o) combine per row-group via LDS (aliased over staging buffer).
// ---------------------------------------------------------------------------
__global__ __launch_bounds__(256, 2) void attn_kernel(const bf16* __restrict__ qhp,
                                                      const bf16* __restrict__ qlp,
                                                      const bf16* __restrict__ khp,
                                                      const bf16* __restrict__ klp,
                                                      const bf16* __restrict__ vp,
                                                      float* __restrict__ out) {
  __shared__ __align__(16) char smem[49152];    // KH | KL | VS (16KB each)
  bf16* KH = (bf16*)smem;                        // [64s][128h] chunk-swizzled
  bf16* KL = KH + 8192;
  bf16* VS = KL + 8192;                          // [128h][64s] chunk-swizzled
  float (*Osum)[16][132] = (float(*)[16][132])smem; // combine alias (16.9KB)
  __shared__ __align__(16) bf16 Pl[4][16][72];  // per-wave P [q][s], padded
  __shared__ float Ml[4][16], Ll[4][16];

  const int tid = threadIdx.x, lane = tid & 63, wave = tid >> 6;
  const int g = lane >> 4, q15 = lane & 15;
  const int x7 = q15 & 7;
  const int bb = blockIdx.x;
  const int batch = bb & 7;                  // block->XCD round-robin: pins L2
  const int i = bb >> 3;
  const int qt = (i < 32) ? (63 - i) : (i - 32); // heavy first, then light
  const int q0 = qt * 32;
  const int gidx = wave >> 1, par = wave & 1;
  const int qrow = q0 + gidx * 16 + q15;

  const bf16* qbh = qhp + (size_t)batch * T * H;
  const bf16* qbl = qlp + (size_t)batch * T * H;
  const bf16* kbh = khp + (size_t)batch * T * H;
  const bf16* kbl = klp + (size_t)batch * T * H;
  const bf16* vb  = vp  + (size_t)batch * H * T;
  float* ob = out + (size_t)batch * T * H;

  // staging geometry (as R5): 16 units of 1KB per array, wave stages 4 units.
  int koff[4], voff[4];
#pragma unroll
  for (int ii = 0; ii < 4; ++ii) {
    const int u = wave * 4 + ii;
    const int r = u * 4 + (lane >> 4);
    const int qk = (lane & 15) ^ (r & 7);
    koff[ii] = r * H + qk * 8;
    const int h = u * 8 + (lane >> 3);
    const int qv = (lane & 7) ^ (h & 7);
    voff[ii] = h * T + qv * 8;
  }
  const int lb = wave * 4 * 512 + lane * 8;

  bf16x8 rkh[4], rkl[4], rv[4];

#define LOADT(S0)                                                     \
  _Pragma("unroll")                                                   \
  for (int ii = 0; ii < 4; ++ii) {                                    \
    rkh[ii] = *(const bf16x8*)&kbh[(size_t)(S0) * H + koff[ii]];      \
    rkl[ii] = *(const bf16x8*)&kbl[(size_t)(S0) * H + koff[ii]];      \
    rv[ii]  = *(const bf16x8*)&vb[(size_t)(S0) + voff[ii]];           \
  }
#define WRITET()                                                      \
  _Pragma("unroll")                                                   \
  for (int ii = 0; ii < 4; ++ii) {                                    \
    *(bf16x8*)&KH[lb + ii * 512] = rkh[ii];                           \
    *(bf16x8*)&KL[lb + ii * 512] = rkl[ii];                           \
    *(bf16x8*)&VS[lb + ii * 512] = rv[ii];                            \
  }

  // Q B-frags hoisted: col = q (lane&15), k = h contiguous
  bf16x8 qfh[4], qfl[4];
#pragma unroll
  for (int k4 = 0; k4 < 4; ++k4) {
    qfh[k4] = *(const bf16x8*)&qbh[(size_t)qrow * H + k4 * 32 + g * 8];
    qfl[k4] = *(const bf16x8*)&qbl[(size_t)qrow * H + k4 * 32 + g * 8];
  }

  f32x4 o[8] = {};
  float mrun = -1e30f, lrun = 0.f;
  const int nt = ((q0 + 31) >> 6) + 1;

  LOADT(0);
  WRITET();
  __syncthreads();

  for (int j = 0; j < nt; ++j) {
    const int s0 = j * 64;
    if (j + 1 < nt) LOADT(s0 + 64);      // prefetch to regs (T14 issue-early)

    if (((j ^ wave) & 1) == 0) {         // this wave's s-parity
      // S^T[s][q]: A = K rows from LDS (swizzled), B = Q.  3-term split.
      f32x4 sacc[4] = {};
#pragma unroll
      for (int mt = 0; mt < 4; ++mt) {
        const int row = mt * 16 + q15;
#pragma unroll
        for (int k4 = 0; k4 < 4; ++k4) {
          const int pch = (k4 * 4 + g) ^ x7;
          const bf16x8 kfh = *(const bf16x8*)&KH[row * 128 + pch * 8];
          const bf16x8 kfl = *(const bf16x8*)&KL[row * 128 + pch * 8];
          sacc[mt] = MFMA16(kfh, qfh[k4], sacc[mt]);
          sacc[mt] = MFMA16(kfl, qfh[k4], sacc[mt]);
          sacc[mt] = MFMA16(kfh, qfl[k4], sacc[mt]);
        }
      }
      if (j == nt - 1) {                 // diagonal only in last tile
#pragma unroll
        for (int mt = 0; mt < 4; ++mt)
#pragma unroll
          for (int r = 0; r < 4; ++r)
            if (s0 + mt * 16 + g * 4 + r > qrow) sacc[mt][r] = -1e30f;
      }
      // online softmax: lane owns one q row (shfl 16/32 reduce)
      float tmax = -1e30f;
#pragma unroll
      for (int mt = 0; mt < 4; ++mt)
#pragma unroll
        for (int r = 0; r < 4; ++r) tmax = fmaxf(tmax, sacc[mt][r]);
      tmax = fmaxf(tmax, __shfl_xor(tmax, 16));
      tmax = fmaxf(tmax, __shfl_xor(tmax, 32));
      const float mnew = fmaxf(mrun, tmax);
      const float alpha = __expf(mrun - mnew);
      float lt = 0.f;
#pragma unroll
      for (int mt = 0; mt < 4; ++mt) {
        bf16x4 pk;
#pragma unroll
        for (int r = 0; r < 4; ++r) {
          const float p = __expf(sacc[mt][r] - mnew);
          lt += p;
          pk[r] = (bf16)p;
        }
        *(bf16x4*)&Pl[wave][q15][mt * 16 + g * 4] = pk; // own-wave slice
      }
      lt += __shfl_xor(lt, 16);
      lt += __shfl_xor(lt, 32);
      lrun = lrun * alpha + lt;
      mrun = mnew;
#pragma unroll
      for (int ii = 0; ii < 8; ++ii) o[ii] *= alpha;
      const bf16x8 pf0 = *(const bf16x8*)&Pl[wave][q15][g * 8];
      const bf16x8 pf1 = *(const bf16x8*)&Pl[wave][q15][32 + g * 8];
      // out^T += V^T * P^T  (A = V rows [h][s] from LDS, swizzled)
#pragma unroll
      for (int mt = 0; mt < 8; ++mt) {
        const int h = mt * 16 + q15;
        const int p0 = g ^ x7, p1 = (4 + g) ^ x7;
        const bf16x8 vf0 = *(const bf16x8*)&VS[h * 64 + p0 * 8];
        o[mt] = MFMA16(vf0, pf0, o[mt]);
        const bf16x8 vf1 = *(const bf16x8*)&VS[h * 64 + p1 * 8];
        o[mt] = MFMA16(vf1, pf1, o[mt]);
      }
    }

    if (j + 1 < nt) {
      __syncthreads();   // all reads of current tile done
      WRITET();          // commit prefetched tile
      __syncthreads();   // tile ready
    }
  }

  // ---- 2-way combine per 16-row group (parity 0 merges parity 1) ----
  if (lane < 16) { Ml[wave][lane] = mrun; Ll[wave][lane] = lrun; }
  __syncthreads();                       // also: staging reads all complete
  const float ma = Ml[gidx * 2][q15], mb = Ml[gidx * 2 + 1][q15];
  const float mg = fmaxf(ma, mb);
  const float ls = Ll[gidx * 2][q15] * __expf(ma - mg)
                 + Ll[gidx * 2 + 1][q15] * __expf(mb - mg);
  const float sc = __expf(mrun - mg);
#pragma unroll
  for (int ii = 0; ii < 8; ++ii) o[ii] *= sc;
  if (par == 1) {
#pragma unroll
    for (int mt = 0; mt < 8; ++mt)
      *(f32x4*)&Osum[gidx][q15][mt * 16 + g * 4] = o[mt];
  }
  __syncthreads();
  if (par == 0) {
    const float inv = 1.0f / ls;
#pragma unroll
    for (int mt = 0; mt < 8; ++mt) {
      f32x4 pk;
#pragma unroll
      for (int r = 0; r < 4; ++r)
        pk[r] = (o[mt][r] + Osum[gidx][q15][mt * 16 + g * 4 + r]) * inv;
      *(f32x4*)&ob[(size_t)qrow * H + mt * 16 + g * 4] = pk;
    }
  }
#undef LOADT
#undef WRITET
}

// ---------------------------------------------------------------------------
extern "C" void kernel_launch(void* const* d_in, const int* in_sizes, int n_in,
                              void* d_out, int out_size, void* d_ws, size_t ws_size,
                              hipStream_t stream) {
  const float* x  = (const float*)d_in[0];   // fp32 inputs per reference
  const float* Wq = (const float*)d_in[1];
  const float* Wk = (const float*)d_in[2];
  const float* Wv = (const float*)d_in[3];
  float* out = (float*)d_out;                // fp32 output

  bf16* wth = (bf16*)d_ws;                   // 3*H*C
  bf16* wtl = wth + (size_t)3 * H * C;       // 3*H*C
  bf16* qh  = wtl + (size_t)3 * H * C;       // M*H each below
  bf16* ql  = qh + (size_t)M * H;
  bf16* kh  = ql + (size_t)M * H;
  bf16* kl  = kh + (size_t)M * H;
  bf16* vt  = kl + (size_t)M * H;            // [B][H][T]

  kwt<<<dim3(C / 32, H / 32, 3), 256, 0, stream>>>(Wq, Wk, Wv, wth, wtl);
  proj_kernel<<<dim3(M / 64, 3), 256, 0, stream>>>(x, wth, wtl, qh, ql, kh, kl, vt);
  attn_kernel<<<512, 256, 0, stream>>>(qh, ql, kh, kl, vt, out);
}

// Round 7
// 92.860 us; speedup vs baseline: 1.3284x; 1.3284x over previous
//
#include <hip/hip_runtime.h>

typedef __bf16 bf16;
typedef __bf16 bf16x4 __attribute__((ext_vector_type(4)));
typedef __bf16 bf16x8 __attribute__((ext_vector_type(8)));
typedef _Float16 f16;
typedef f16 f16x4 __attribute__((ext_vector_type(4)));
typedef f16 f16x8 __attribute__((ext_vector_type(8)));
typedef float f32x4 __attribute__((ext_vector_type(4)));

#define MFMA_BF(a, b, c) __builtin_amdgcn_mfma_f32_16x16x32_bf16((a), (b), (c), 0, 0, 0)
#define MFMA_FP(a, b, c) __builtin_amdgcn_mfma_f32_16x16x32_f16((a), (b), (c), 0, 0, 0)

static constexpr int Bn = 8, T = 2048, C = 1024, H = 128;
static constexpr int M = Bn * T; // 16384

// ---------------------------------------------------------------------------
// Kernel 0: transpose + hi/lo split  W[C][H] fp32 -> wt_hi/wt_lo [3][H][C] bf16
// ---------------------------------------------------------------------------
__global__ __launch_bounds__(256) void kwt(const float* __restrict__ Wq,
                                           const float* __restrict__ Wk,
                                           const float* __restrict__ Wv,
                                           bf16* __restrict__ wth,
                                           bf16* __restrict__ wtl) {
  __shared__ float tl[32][33];
  const int w = blockIdx.z;
  const float* src = (w == 0) ? Wq : (w == 1) ? Wk : Wv;
  bf16* dh = wth + (size_t)w * H * C;
  bf16* dl = wtl + (size_t)w * H * C;
  const int k0 = blockIdx.x * 32, n0 = blockIdx.y * 32;
  const int tx = threadIdx.x & 31, ty = threadIdx.x >> 5; // 32 x 8
  for (int i = ty; i < 32; i += 8) tl[i][tx] = src[(size_t)(k0 + i) * H + n0 + tx];
  __syncthreads();
  for (int i = ty; i < 32; i += 8) {
    float v = tl[tx][i];
    bf16 h = (bf16)v;
    bf16 l = (bf16)(v - (float)h);
    dh[(size_t)(n0 + i) * C + k0 + tx] = h;
    dl[(size_t)(n0 + i) * C + k0 + tx] = l;
  }
}

// ---------------------------------------------------------------------------
// Kernel 1: QKV projection, split-bf16 3-term for ALL of q,k,v (accuracy),
// outputs fp16.  grid (M/64, 3).  256 thr = 4 waves (2x2).  Tile 64x128, BK=64.
// y==0 -> q fp16 [t][h]; y==1 -> k fp16 [t][h]; y==2 -> v fp16 transposed [b][h][t].
// ---------------------------------------------------------------------------
__global__ __launch_bounds__(256) void proj_kernel(const float* __restrict__ x,
                                                   const bf16* __restrict__ wth,
                                                   const bf16* __restrict__ wtl,
                                                   f16* __restrict__ qo,
                                                   f16* __restrict__ ko,
                                                   f16* __restrict__ vt) {
  __shared__ __align__(16) bf16 Ah[64 * 72], Al[64 * 72];    // [m][k] padded
  __shared__ __align__(16) bf16 Bh[128 * 72], Bl[128 * 72];  // [n][k] padded
  const int tid = threadIdx.x;
  const int lane = tid & 63, g = lane >> 4, r16 = lane & 15;
  const int wave = tid >> 6, wr = wave >> 1, wc = wave & 1;
  const int m0 = blockIdx.x * 64;
  const int which = blockIdx.y;
  const bf16* wh = wth + (size_t)which * H * C;
  const bf16* wl = wtl + (size_t)which * H * C;

  int am[4], ak[4], bn[4], bk[4];
#pragma unroll
  for (int it = 0; it < 4; ++it) {
    int c = it * 256 + tid;
    am[it] = c >> 4; ak[it] = (c & 15) << 2;
    bn[it] = c >> 3; bk[it] = (c & 7) << 3;
  }

  f32x4 ra[4]; bf16x8 rbh[4], rbl[4];
#pragma unroll
  for (int it = 0; it < 4; ++it) {
    ra[it]  = *(const f32x4*)&x[(size_t)(m0 + am[it]) * C + ak[it]];
    rbh[it] = *(const bf16x8*)&wh[(size_t)bn[it] * C + bk[it]];
    rbl[it] = *(const bf16x8*)&wl[(size_t)bn[it] * C + bk[it]];
  }

  f32x4 acc[2][4] = {};

  for (int k0 = 0; k0 < C; k0 += 64) {
    __syncthreads();
#pragma unroll
    for (int it = 0; it < 4; ++it) {
      bf16x4 hv, lv;
#pragma unroll
      for (int j = 0; j < 4; ++j) {
        float v = ra[it][j];
        bf16 h = (bf16)v;
        hv[j] = h;
        lv[j] = (bf16)(v - (float)h);
      }
      *(bf16x4*)&Ah[am[it] * 72 + ak[it]] = hv;
      *(bf16x4*)&Al[am[it] * 72 + ak[it]] = lv;
      *(bf16x8*)&Bh[bn[it] * 72 + bk[it]] = rbh[it];
      *(bf16x8*)&Bl[bn[it] * 72 + bk[it]] = rbl[it];
    }
    if (k0 + 64 < C) {
      const int kn = k0 + 64;
#pragma unroll
      for (int it = 0; it < 4; ++it) {
        ra[it]  = *(const f32x4*)&x[(size_t)(m0 + am[it]) * C + kn + ak[it]];
        rbh[it] = *(const bf16x8*)&wh[(size_t)bn[it] * C + kn + bk[it]];
        rbl[it] = *(const bf16x8*)&wl[(size_t)bn[it] * C + kn + bk[it]];
      }
    }
    __syncthreads();
#pragma unroll
    for (int kb = 0; kb < 2; ++kb) {
      bf16x8 afh[2], afl[2], bfh[4], bfl[4];
#pragma unroll
      for (int mt = 0; mt < 2; ++mt) {
        const int ro = (wr * 32 + mt * 16 + r16) * 72 + kb * 32 + g * 8;
        afh[mt] = *(const bf16x8*)&Ah[ro];
        afl[mt] = *(const bf16x8*)&Al[ro];
      }
#pragma unroll
      for (int nt = 0; nt < 4; ++nt) {
        const int ro = (wc * 64 + nt * 16 + r16) * 72 + kb * 32 + g * 8;
        bfh[nt] = *(const bf16x8*)&Bh[ro];
        bfl[nt] = *(const bf16x8*)&Bl[ro];
      }
#pragma unroll
      for (int mt = 0; mt < 2; ++mt)
#pragma unroll
        for (int nt = 0; nt < 4; ++nt) {
          acc[mt][nt] = MFMA_BF(afh[mt], bfh[nt], acc[mt][nt]);
          acc[mt][nt] = MFMA_BF(afl[mt], bfh[nt], acc[mt][nt]);
          acc[mt][nt] = MFMA_BF(afh[mt], bfl[nt], acc[mt][nt]);
        }
    }
  }

  // epilogue.  C/D frag: col = lane&15, row = (lane>>4)*4 + reg  [m89]
  if (which < 2) {
    f16* dst = which ? ko : qo;
#pragma unroll
    for (int mt = 0; mt < 2; ++mt)
#pragma unroll
      for (int nt = 0; nt < 4; ++nt) {
        const int mb = m0 + wr * 32 + mt * 16 + g * 4;
        const int col = wc * 64 + nt * 16 + r16;
#pragma unroll
        for (int r = 0; r < 4; ++r)
          dst[(size_t)(mb + r) * H + col] = (f16)acc[mt][nt][r];
      }
  } else {
    const int b = m0 >> 11;
    const int tb0 = m0 & 2047;
    f16* vbase = vt + (size_t)b * H * T;
#pragma unroll
    for (int mt = 0; mt < 2; ++mt)
#pragma unroll
      for (int nt = 0; nt < 4; ++nt) {
        const int tib = tb0 + wr * 32 + mt * 16 + g * 4;
        const int h = wc * 64 + nt * 16 + r16;
        f16x4 pk;
#pragma unroll
        for (int r = 0; r < 4; ++r) pk[r] = (f16)acc[mt][nt][r];
        *(f16x4*)&vbase[(size_t)h * T + tib] = pk;
      }
  }
}

// ---------------------------------------------------------------------------
// Kernel 2: causal flash attention, fp16, block-level s-parity split.
// 512 blocks: b = bb&7 (XCD-pinned), qt = 31-(bb>>4) (heavy first, LPT),
// par = (bb>>3)&1.  Block = 64 q-rows (4 waves x 16), processes s-tiles
// j = par, par+2, ... <= qt.  K [64][128] + V^T [128][64] fp16 double-buffered
// in LDS (XOR chunk-swizzle), ONE barrier per tile.  1-term fp16 QK^T; P fp16.
// par0 writes normalized O (f32) to d_out; par1 to scratch; combine merges.
// ---------------------------------------------------------------------------
__global__ __launch_bounds__(256, 2) void attn_kernel(const f16* __restrict__ qp,
                                                      const f16* __restrict__ kp,
                                                      const f16* __restrict__ vp,
                                                      float* __restrict__ out,
                                                      f16* __restrict__ oS,
                                                      float* __restrict__ MLs) {
  __shared__ __align__(16) f16 KS[2][64 * 128];   // [s][h], chunk-swizzled
  __shared__ __align__(16) f16 VS[2][128 * 64];   // [h][s], chunk-swizzled
  __shared__ __align__(16) f16 Pl[4][16][72];     // per-wave P [q][s], padded

  const int tid = threadIdx.x, lane = tid & 63, wave = tid >> 6;
  const int g = lane >> 4, q15 = lane & 15;
  const int x7 = q15 & 7;
  const int bb = blockIdx.x;
  const int b = bb & 7;                 // block->XCD round-robin: pins batch L2
  const int t2 = bb >> 3;               // 0..63
  const int qt = 31 - (t2 >> 1);        // heavy tasks dispatch first (LPT)
  const int par = t2 & 1;
  const int q0 = qt * 64;
  const int qrow = q0 + wave * 16 + q15;
  const int task = b * 32 + qt;

  const f16* qb = qp + (size_t)b * T * H;
  const f16* kb = kp + (size_t)b * T * H;
  const f16* vb = vp + (size_t)b * H * T;

  // staging: K 16KB = 16 units of 1KB (4 rows x 256B); V 16KB = 16 units
  // (8 rows x 128B).  Wave stages units wave*4+i.  LDS dest linear; source
  // chunk pre-XOR'd so reads with phys = c ^ (row&7) are conflict-free.
  int koff[4], voff[4], lo[4];
#pragma unroll
  for (int i = 0; i < 4; ++i) {
    const int u = wave * 4 + i;
    const int rK = u * 4 + (lane >> 4);
    koff[i] = rK * H + (((lane & 15) ^ (rK & 7)) << 3);
    const int hV = u * 8 + (lane >> 3);
    voff[i] = hV * T + (((lane & 7) ^ (hV & 7)) << 3);
    lo[i] = u * 512 + lane * 8;
  }

  const int n = (qt >= par) ? ((qt - par) >> 1) + 1 : 0;   // my tile count

  // Q frags hoisted: col = q (lane&15), k = h contiguous
  f16x8 qf[4];
#pragma unroll
  for (int k4 = 0; k4 < 4; ++k4)
    qf[k4] = *(const f16x8*)&qb[(size_t)qrow * H + k4 * 32 + g * 8];

  f32x4 o[8] = {};
  float mrun = -1e30f, lrun = 0.f;

  f16x8 rk[4], rv[4];
#define LOADT(S0)                                                   \
  _Pragma("unroll")                                                 \
  for (int i = 0; i < 4; ++i) {                                     \
    rk[i] = *(const f16x8*)&kb[(size_t)(S0) * H + koff[i]];         \
    rv[i] = *(const f16x8*)&vb[(size_t)(S0) + voff[i]];             \
  }
#define WRITET(BUF)                                                 \
  _Pragma("unroll")                                                 \
  for (int i = 0; i < 4; ++i) {                                     \
    *(f16x8*)&KS[BUF][lo[i]] = rk[i];                               \
    *(f16x8*)&VS[BUF][lo[i]] = rv[i];                               \
  }

  if (n > 0) {
    LOADT(par * 64);
    WRITET(0);
    if (n > 1) LOADT(par * 64 + 128);

    for (int k = 0; k < n; ++k) {
      const int s0 = par * 64 + k * 128;
      const int cur = k & 1;
      __syncthreads();  // WRITET(cur) by all waves complete

      // S^T[s][q]: A = K rows from LDS, B = Q.  Single fp16 term.
      f32x4 sacc[4] = {};
#pragma unroll
      for (int mt = 0; mt < 4; ++mt) {
        const int row = mt * 16 + q15;
#pragma unroll
        for (int k4 = 0; k4 < 4; ++k4) {
          const int pch = (k4 * 4 + g) ^ (row & 7);
          const f16x8 kf = *(const f16x8*)&KS[cur][row * 128 + pch * 8];
          sacc[mt] = MFMA_FP(kf, qf[k4], sacc[mt]);
        }
      }
      if (k == n - 1) {  // my last tile is the diagonal tile (j == qt)
#pragma unroll
        for (int mt = 0; mt < 4; ++mt)
#pragma unroll
          for (int r = 0; r < 4; ++r)
            if (s0 + mt * 16 + g * 4 + r > qrow) sacc[mt][r] = -1e30f;
      }
      // online softmax: lane owns one q row (shfl 16/32 reduce)
      float tmax = -1e30f;
#pragma unroll
      for (int mt = 0; mt < 4; ++mt)
#pragma unroll
        for (int r = 0; r < 4; ++r) tmax = fmaxf(tmax, sacc[mt][r]);
      tmax = fmaxf(tmax, __shfl_xor(tmax, 16));
      tmax = fmaxf(tmax, __shfl_xor(tmax, 32));
      const float mnew = fmaxf(mrun, tmax);
      const float alpha = __expf(mrun - mnew);
      float lt = 0.f;
#pragma unroll
      for (int mt = 0; mt < 4; ++mt) {
        f16x4 pk;
#pragma unroll
        for (int r = 0; r < 4; ++r) {
          const float p = __expf(sacc[mt][r] - mnew);
          lt += p;
          pk[r] = (f16)p;
        }
        *(f16x4*)&Pl[wave][q15][mt * 16 + g * 4] = pk;  // own-wave slice
      }
      lt += __shfl_xor(lt, 16);
      lt += __shfl_xor(lt, 32);
      lrun = lrun * alpha + lt;
      mrun = mnew;
#pragma unroll
      for (int i = 0; i < 8; ++i) o[i] *= alpha;
      const f16x8 pf0 = *(const f16x8*)&Pl[wave][q15][g * 8];
      const f16x8 pf1 = *(const f16x8*)&Pl[wave][q15][32 + g * 8];
      // out^T += V^T * P^T  (A = V rows [h][s] from LDS)
#pragma unroll
      for (int mt = 0; mt < 8; ++mt) {
        const int h = mt * 16 + q15;
        const f16x8 vf0 = *(const f16x8*)&VS[cur][h * 64 + ((g ^ x7) << 3)];
        o[mt] = MFMA_FP(vf0, pf0, o[mt]);
        const f16x8 vf1 = *(const f16x8*)&VS[cur][h * 64 + (((4 + g) ^ x7) << 3)];
        o[mt] = MFMA_FP(vf1, pf1, o[mt]);
      }

      // write NEXT tile into the other buffer: its previous readers (iter k-1)
      // all passed this iteration's barrier -> safe; one barrier per tile.
      if (k + 1 < n) {
        WRITET(cur ^ 1);
        if (k + 2 < n) LOADT(par * 64 + (k + 2) * 128);
      }
    }
  }
#undef LOADT
#undef WRITET

  // epilogue: normalized O.  par0 -> d_out (f32); par1 -> scratch (fp16).
  const float inv = (lrun > 0.f) ? 1.0f / lrun : 0.f;
  if (lane < 16) {
    MLs[((size_t)(task * 2 + par) * 64 + wave * 16 + lane) * 2 + 0] = mrun;
    MLs[((size_t)(task * 2 + par) * 64 + wave * 16 + lane) * 2 + 1] = lrun;
  }
  if (par == 0) {
    float* ob = out + ((size_t)b * T + qrow) * H;
#pragma unroll
    for (int mt = 0; mt < 8; ++mt) {
      f32x4 pk;
#pragma unroll
      for (int r = 0; r < 4; ++r) pk[r] = o[mt][r] * inv;
      *(f32x4*)&ob[mt * 16 + g * 4] = pk;
    }
  } else {
    f16* sb = oS + ((size_t)task * 64 + wave * 16 + q15) * 128;
#pragma unroll
    for (int mt = 0; mt < 8; ++mt) {
      f16x4 pk;
#pragma unroll
      for (int r = 0; r < 4; ++r) pk[r] = (f16)(o[mt][r] * inv);
      *(f16x4*)&sb[mt * 16 + g * 4] = pk;
    }
  }
}

// ---------------------------------------------------------------------------
// Kernel 3: combine the two parity partials per task (flash merge), in-place
// on d_out.  256 blocks x 256 thr; thread = (row = tid>>2, 32-col slice).
// ---------------------------------------------------------------------------
__global__ __launch_bounds__(256) void combine_kernel(float* __restrict__ out,
                                                      const f16* __restrict__ oS,
                                                      const float* __restrict__ MLs) {
  const int task = blockIdx.x;           // b*32 + qt
  const int b = task >> 5, qt = task & 31;
  const int tid = threadIdx.x;
  const int row = tid >> 2;
  const int cb = (tid & 3) * 32;
  const float m0 = MLs[((size_t)(task * 2 + 0) * 64 + row) * 2 + 0];
  const float l0 = MLs[((size_t)(task * 2 + 0) * 64 + row) * 2 + 1];
  const float m1 = MLs[((size_t)(task * 2 + 1) * 64 + row) * 2 + 0];
  const float l1 = MLs[((size_t)(task * 2 + 1) * 64 + row) * 2 + 1];
  const float Mg = fmaxf(m0, m1);
  const float w0 = l0 * __expf(m0 - Mg);
  const float w1 = l1 * __expf(m1 - Mg);
  const float inv = 1.0f / (w0 + w1);
  float* orow = out + ((size_t)b * T + qt * 64 + row) * H + cb;
  const f16* srow = oS + ((size_t)task * 64 + row) * 128 + cb;
#pragma unroll
  for (int c = 0; c < 32; c += 8) {
    const f16x8 o1 = *(const f16x8*)&srow[c];
    f32x4 a0 = *(const f32x4*)&orow[c];
    f32x4 a1 = *(const f32x4*)&orow[c + 4];
    f32x4 r0, r1;
#pragma unroll
    for (int r = 0; r < 4; ++r) {
      r0[r] = (w0 * a0[r] + w1 * (float)o1[r]) * inv;
      r1[r] = (w0 * a1[r] + w1 * (float)o1[4 + r]) * inv;
    }
    *(f32x4*)&orow[c] = r0;
    *(f32x4*)&orow[c + 4] = r1;
  }
}

// ---------------------------------------------------------------------------
extern "C" void kernel_launch(void* const* d_in, const int* in_sizes, int n_in,
                              void* d_out, int out_size, void* d_ws, size_t ws_size,
                              hipStream_t stream) {
  const float* x  = (const float*)d_in[0];   // fp32 inputs per reference
  const float* Wq = (const float*)d_in[1];
  const float* Wk = (const float*)d_in[2];
  const float* Wv = (const float*)d_in[3];
  float* out = (float*)d_out;                // fp32 output

  bf16* wth = (bf16*)d_ws;                            // 3*H*C bf16
  bf16* wtl = wth + (size_t)3 * H * C;                // 3*H*C bf16
  f16*  qf  = (f16*)(wtl + (size_t)3 * H * C);        // M*H fp16
  f16*  kf  = qf + (size_t)M * H;                     // M*H fp16
  f16*  vf  = kf + (size_t)M * H;                     // M*H fp16 [b][h][t]
  f16*  oS  = vf + (size_t)M * H;                     // 256*64*128 fp16
  float* MLs = (float*)(oS + (size_t)256 * 64 * 128); // 256*2*64*2 f32

  kwt<<<dim3(C / 32, H / 32, 3), 256, 0, stream>>>(Wq, Wk, Wv, wth, wtl);
  proj_kernel<<<dim3(M / 64, 3), 256, 0, stream>>>(x, wth, wtl, qf, kf, vf);
  attn_kernel<<<512, 256, 0, stream>>>(qf, kf, vf, out, oS, MLs);
  combine_kernel<<<256, 256, 0, stream>>>(out, oS, MLs);
}

// Round 8
// 67.518 us; speedup vs baseline: 1.8271x; 1.3753x over previous
//
#include <hip/hip_runtime.h>

typedef __bf16 bf16;
typedef _Float16 f16;
typedef f16 f16x4 __attribute__((ext_vector_type(4)));
typedef f16 f16x8 __attribute__((ext_vector_type(8)));
typedef float f32x4 __attribute__((ext_vector_type(4)));

#define MFMA_FP(a, b, c) __builtin_amdgcn_mfma_f32_16x16x32_f16((a), (b), (c), 0, 0, 0)

static constexpr int Bn = 8, T = 2048, C = 1024, H = 128;
static constexpr int M = Bn * T; // 16384

// ---------------------------------------------------------------------------
// Kernel 0: transpose  W[C][H] fp32 -> wt [3][H][C] fp16 (single plane)
// ---------------------------------------------------------------------------
__global__ __launch_bounds__(256) void kwt(const float* __restrict__ Wq,
                                           const float* __restrict__ Wk,
                                           const float* __restrict__ Wv,
                                           f16* __restrict__ wt) {
  __shared__ float tl[32][33];
  const int w = blockIdx.z;
  const float* src = (w == 0) ? Wq : (w == 1) ? Wk : Wv;
  f16* dh = wt + (size_t)w * H * C;
  const int k0 = blockIdx.x * 32, n0 = blockIdx.y * 32;
  const int tx = threadIdx.x & 31, ty = threadIdx.x >> 5; // 32 x 8
  for (int i = ty; i < 32; i += 8) tl[i][tx] = src[(size_t)(k0 + i) * H + n0 + tx];
  __syncthreads();
  for (int i = ty; i < 32; i += 8)
    dh[(size_t)(n0 + i) * C + k0 + tx] = (f16)tl[tx][i];
}

// ---------------------------------------------------------------------------
// Kernel 1: QKV projection, single-term fp16 (f32 accumulate).
// grid (M/64, 3) = 768 blocks (exactly 3/CU).  256 thr = 4 waves (2x2).
// Tile 64m x 128n, BK=64.  LDS XOR chunk-swizzle (phys = c ^ (row&7)),
// row stride 64 fp16 = 128B -> conflict-free b128 reads and writes.
// y==0 -> q fp16 [t][h]; y==1 -> k fp16; y==2 -> v fp16 transposed [b][h][t].
// ---------------------------------------------------------------------------
__global__ __launch_bounds__(256) void proj_kernel(const float* __restrict__ x,
                                                   const f16* __restrict__ wt,
                                                   f16* __restrict__ qo,
                                                   f16* __restrict__ ko,
                                                   f16* __restrict__ vt) {
  __shared__ __align__(16) f16 As[64 * 64];    // [m][k] swizzled, 8KB
  __shared__ __align__(16) f16 Bs[128 * 64];   // [n][k] swizzled, 16KB
  const int tid = threadIdx.x;
  const int lane = tid & 63, g = lane >> 4, r16 = lane & 15;
  const int wave = tid >> 6, wr = wave >> 1, wc = wave & 1;
  const int m0 = blockIdx.x * 64;
  const int which = blockIdx.y;
  const f16* wh = wt + (size_t)which * H * C;

  // staging chunk coords (8 fp16 per chunk).  A: 512 chunks, B: 1024 chunks.
  int arow[2], aoff[2], alds[2];
  int brow[4], boff[4], blds[4];
#pragma unroll
  for (int it = 0; it < 2; ++it) {
    const int c = it * 256 + tid, r = c >> 3, p = c & 7;
    arow[it] = r; aoff[it] = ((p ^ (r & 7)) << 3); alds[it] = r * 64 + p * 8;
  }
#pragma unroll
  for (int it = 0; it < 4; ++it) {
    const int c = it * 256 + tid, r = c >> 3, p = c & 7;
    brow[it] = r; boff[it] = ((p ^ (r & 7)) << 3); blds[it] = r * 64 + p * 8;
  }

  f32x4 ra[2][2]; f16x8 rb[4];
#pragma unroll
  for (int it = 0; it < 2; ++it) {
    ra[it][0] = *(const f32x4*)&x[(size_t)(m0 + arow[it]) * C + aoff[it]];
    ra[it][1] = *(const f32x4*)&x[(size_t)(m0 + arow[it]) * C + aoff[it] + 4];
  }
#pragma unroll
  for (int it = 0; it < 4; ++it)
    rb[it] = *(const f16x8*)&wh[(size_t)brow[it] * C + boff[it]];

  f32x4 acc[2][4] = {};

  for (int k0 = 0; k0 < C; k0 += 64) {
    __syncthreads();
#pragma unroll
    for (int it = 0; it < 2; ++it) {
      f16x8 av;
#pragma unroll
      for (int j = 0; j < 4; ++j) { av[j] = (f16)ra[it][0][j]; av[4 + j] = (f16)ra[it][1][j]; }
      *(f16x8*)&As[alds[it]] = av;
    }
#pragma unroll
    for (int it = 0; it < 4; ++it) *(f16x8*)&Bs[blds[it]] = rb[it];
    if (k0 + 64 < C) {
      const int kn = k0 + 64;
#pragma unroll
      for (int it = 0; it < 2; ++it) {
        ra[it][0] = *(const f32x4*)&x[(size_t)(m0 + arow[it]) * C + kn + aoff[it]];
        ra[it][1] = *(const f32x4*)&x[(size_t)(m0 + arow[it]) * C + kn + aoff[it] + 4];
      }
#pragma unroll
      for (int it = 0; it < 4; ++it)
        rb[it] = *(const f16x8*)&wh[(size_t)brow[it] * C + kn + boff[it]];
    }
    __syncthreads();
#pragma unroll
    for (int kb = 0; kb < 2; ++kb) {
      f16x8 af[2], bf[4];
#pragma unroll
      for (int mt = 0; mt < 2; ++mt) {
        const int r = wr * 32 + mt * 16 + r16;
        const int phys = (kb * 4 + g) ^ (r & 7);
        af[mt] = *(const f16x8*)&As[r * 64 + phys * 8];
      }
#pragma unroll
      for (int nt = 0; nt < 4; ++nt) {
        const int r = wc * 64 + nt * 16 + r16;
        const int phys = (kb * 4 + g) ^ (r & 7);
        bf[nt] = *(const f16x8*)&Bs[r * 64 + phys * 8];
      }
#pragma unroll
      for (int mt = 0; mt < 2; ++mt)
#pragma unroll
        for (int nt = 0; nt < 4; ++nt)
          acc[mt][nt] = MFMA_FP(af[mt], bf[nt], acc[mt][nt]);
    }
  }

  // epilogue.  C/D frag: col = lane&15, row = (lane>>4)*4 + reg  [m89]
  if (which < 2) {
    f16* dst = which ? ko : qo;
#pragma unroll
    for (int mt = 0; mt < 2; ++mt)
#pragma unroll
      for (int nt = 0; nt < 4; ++nt) {
        const int mb = m0 + wr * 32 + mt * 16 + g * 4;
        const int col = wc * 64 + nt * 16 + r16;
#pragma unroll
        for (int r = 0; r < 4; ++r)
          dst[(size_t)(mb + r) * H + col] = (f16)acc[mt][nt][r];
      }
  } else {
    const int b = m0 >> 11;
    const int tb0 = m0 & 2047;
    f16* vbase = vt + (size_t)b * H * T;
#pragma unroll
    for (int mt = 0; mt < 2; ++mt)
#pragma unroll
      for (int nt = 0; nt < 4; ++nt) {
        const int tib = tb0 + wr * 32 + mt * 16 + g * 4;
        const int h = wc * 64 + nt * 16 + r16;
        f16x4 pk;
#pragma unroll
        for (int r = 0; r < 4; ++r) pk[r] = (f16)acc[mt][nt][r];
        *(f16x4*)&vbase[(size_t)h * T + tib] = pk;
      }
  }
}

// ---------------------------------------------------------------------------
// Kernel 2: causal flash attention, fp16, block-level s-parity split.
// 512 blocks: b = bb&7 (XCD-pinned), qt = 31-(bb>>4) (heavy first, LPT),
// par = (bb>>3)&1.  Block = 64 q-rows (4 waves x 16), processes s-tiles
// j = par, par+2, ... <= qt.  K [64][128] + V^T [128][64] fp16 double-buffered
// in LDS (XOR chunk-swizzle), ONE barrier per tile.  1-term fp16 QK^T; P fp16.
// par0 writes normalized O (f32) to d_out; par1 to scratch; combine merges.
// ---------------------------------------------------------------------------
__global__ __launch_bounds__(256, 2) void attn_kernel(const f16* __restrict__ qp,
                                                      const f16* __restrict__ kp,
                                                      const f16* __restrict__ vp,
                                                      float* __restrict__ out,
                                                      f16* __restrict__ oS,
                                                      float* __restrict__ MLs) {
  __shared__ __align__(16) f16 KS[2][64 * 128];   // [s][h], chunk-swizzled
  __shared__ __align__(16) f16 VS[2][128 * 64];   // [h][s], chunk-swizzled
  __shared__ __align__(16) f16 Pl[4][16][72];     // per-wave P [q][s], padded

  const int tid = threadIdx.x, lane = tid & 63, wave = tid >> 6;
  const int g = lane >> 4, q15 = lane & 15;
  const int x7 = q15 & 7;
  const int bb = blockIdx.x;
  const int b = bb & 7;                 // block->XCD round-robin: pins batch L2
  const int t2 = bb >> 3;               // 0..63
  const int qt = 31 - (t2 >> 1);        // heavy tasks dispatch first (LPT)
  const int par = t2 & 1;
  const int q0 = qt * 64;
  const int qrow = q0 + wave * 16 + q15;
  const int task = b * 32 + qt;

  const f16* qb = qp + (size_t)b * T * H;
  const f16* kb = kp + (size_t)b * T * H;
  const f16* vb = vp + (size_t)b * H * T;

  int koff[4], voff[4], lo[4];
#pragma unroll
  for (int i = 0; i < 4; ++i) {
    const int u = wave * 4 + i;
    const int rK = u * 4 + (lane >> 4);
    koff[i] = rK * H + (((lane & 15) ^ (rK & 7)) << 3);
    const int hV = u * 8 + (lane >> 3);
    voff[i] = hV * T + (((lane & 7) ^ (hV & 7)) << 3);
    lo[i] = u * 512 + lane * 8;
  }

  const int n = (qt >= par) ? ((qt - par) >> 1) + 1 : 0;   // my tile count

  f16x8 qf[4];
#pragma unroll
  for (int k4 = 0; k4 < 4; ++k4)
    qf[k4] = *(const f16x8*)&qb[(size_t)qrow * H + k4 * 32 + g * 8];

  f32x4 o[8] = {};
  float mrun = -1e30f, lrun = 0.f;

  f16x8 rk[4], rv[4];
#define LOADT(S0)                                                   \
  _Pragma("unroll")                                                 \
  for (int i = 0; i < 4; ++i) {                                     \
    rk[i] = *(const f16x8*)&kb[(size_t)(S0) * H + koff[i]];         \
    rv[i] = *(const f16x8*)&vb[(size_t)(S0) + voff[i]];             \
  }
#define WRITET(BUF)                                                 \
  _Pragma("unroll")                                                 \
  for (int i = 0; i < 4; ++i) {                                     \
    *(f16x8*)&KS[BUF][lo[i]] = rk[i];                               \
    *(f16x8*)&VS[BUF][lo[i]] = rv[i];                               \
  }

  if (n > 0) {
    LOADT(par * 64);
    WRITET(0);
    if (n > 1) LOADT(par * 64 + 128);

    for (int k = 0; k < n; ++k) {
      const int s0 = par * 64 + k * 128;
      const int cur = k & 1;
      __syncthreads();  // WRITET(cur) by all waves complete

      f32x4 sacc[4] = {};
#pragma unroll
      for (int mt = 0; mt < 4; ++mt) {
        const int row = mt * 16 + q15;
#pragma unroll
        for (int k4 = 0; k4 < 4; ++k4) {
          const int pch = (k4 * 4 + g) ^ (row & 7);
          const f16x8 kf = *(const f16x8*)&KS[cur][row * 128 + pch * 8];
          sacc[mt] = MFMA_FP(kf, qf[k4], sacc[mt]);
        }
      }
      if (k == n - 1) {
#pragma unroll
        for (int mt = 0; mt < 4; ++mt)
#pragma unroll
          for (int r = 0; r < 4; ++r)
            if (s0 + mt * 16 + g * 4 + r > qrow) sacc[mt][r] = -1e30f;
      }
      float tmax = -1e30f;
#pragma unroll
      for (int mt = 0; mt < 4; ++mt)
#pragma unroll
        for (int r = 0; r < 4; ++r) tmax = fmaxf(tmax, sacc[mt][r]);
      tmax = fmaxf(tmax, __shfl_xor(tmax, 16));
      tmax = fmaxf(tmax, __shfl_xor(tmax, 32));
      const float mnew = fmaxf(mrun, tmax);
      const float alpha = __expf(mrun - mnew);
      float lt = 0.f;
#pragma unroll
      for (int mt = 0; mt < 4; ++mt) {
        f16x4 pk;
#pragma unroll
        for (int r = 0; r < 4; ++r) {
          const float p = __expf(sacc[mt][r] - mnew);
          lt += p;
          pk[r] = (f16)p;
        }
        *(f16x4*)&Pl[wave][q15][mt * 16 + g * 4] = pk;
      }
      lt += __shfl_xor(lt, 16);
      lt += __shfl_xor(lt, 32);
      lrun = lrun * alpha + lt;
      mrun = mnew;
#pragma unroll
      for (int i = 0; i < 8; ++i) o[i] *= alpha;
      const f16x8 pf0 = *(const f16x8*)&Pl[wave][q15][g * 8];
      const f16x8 pf1 = *(const f16x8*)&Pl[wave][q15][32 + g * 8];
#pragma unroll
      for (int mt = 0; mt < 8; ++mt) {
        const int h = mt * 16 + q15;
        const f16x8 vf0 = *(const f16x8*)&VS[cur][h * 64 + ((g ^ x7) << 3)];
        o[mt] = MFMA_FP(vf0, pf0, o[mt]);
        const f16x8 vf1 = *(const f16x8*)&VS[cur][h * 64 + (((4 + g) ^ x7) << 3)];
        o[mt] = MFMA_FP(vf1, pf1, o[mt]);
      }

      if (k + 1 < n) {
        WRITET(cur ^ 1);
        if (k + 2 < n) LOADT(par * 64 + (k + 2) * 128);
      }
    }
  }
#undef LOADT
#undef WRITET

  const float inv = (lrun > 0.f) ? 1.0f / lrun : 0.f;
  if (lane < 16) {
    MLs[((size_t)(task * 2 + par) * 64 + wave * 16 + lane) * 2 + 0] = mrun;
    MLs[((size_t)(task * 2 + par) * 64 + wave * 16 + lane) * 2 + 1] = lrun;
  }
  if (par == 0) {
    float* ob = out + ((size_t)b * T + qrow) * H;
#pragma unroll
    for (int mt = 0; mt < 8; ++mt) {
      f32x4 pk;
#pragma unroll
      for (int r = 0; r < 4; ++r) pk[r] = o[mt][r] * inv;
      *(f32x4*)&ob[mt * 16 + g * 4] = pk;
    }
  } else {
    f16* sb = oS + ((size_t)task * 64 + wave * 16 + q15) * 128;
#pragma unroll
    for (int mt = 0; mt < 8; ++mt) {
      f16x4 pk;
#pragma unroll
      for (int r = 0; r < 4; ++r) pk[r] = (f16)(o[mt][r] * inv);
      *(f16x4*)&sb[mt * 16 + g * 4] = pk;
    }
  }
}

// ---------------------------------------------------------------------------
// Kernel 3: combine the two parity partials per task (flash merge), in-place.
// ---------------------------------------------------------------------------
__global__ __launch_bounds__(256) void combine_kernel(float* __restrict__ out,
                                                      const f16* __restrict__ oS,
                                                      const float* __restrict__ MLs) {
  const int task = blockIdx.x;           // b*32 + qt
  const int b = task >> 5, qt = task & 31;
  const int tid = threadIdx.x;
  const int row = tid >> 2;
  const int cb = (tid & 3) * 32;
  const float m0 = MLs[((size_t)(task * 2 + 0) * 64 + row) * 2 + 0];
  const float l0 = MLs[((size_t)(task * 2 + 0) * 64 + row) * 2 + 1];
  const float m1 = MLs[((size_t)(task * 2 + 1) * 64 + row) * 2 + 0];
  const float l1 = MLs[((size_t)(task * 2 + 1) * 64 + row) * 2 + 1];
  const float Mg = fmaxf(m0, m1);
  const float w0 = l0 * __expf(m0 - Mg);
  const float w1 = l1 * __expf(m1 - Mg);
  const float inv = 1.0f / (w0 + w1);
  float* orow = out + ((size_t)b * T + qt * 64 + row) * H + cb;
  const f16* srow = oS + ((size_t)task * 64 + row) * 128 + cb;
#pragma unroll
  for (int c = 0; c < 32; c += 8) {
    const f16x8 o1 = *(const f16x8*)&srow[c];
    f32x4 a0 = *(const f32x4*)&orow[c];
    f32x4 a1 = *(const f32x4*)&orow[c + 4];
    f32x4 r0, r1;
#pragma unroll
    for (int r = 0; r < 4; ++r) {
      r0[r] = (w0 * a0[r] + w1 * (float)o1[r]) * inv;
      r1[r] = (w0 * a1[r] + w1 * (float)o1[4 + r]) * inv;
    }
    *(f32x4*)&orow[c] = r0;
    *(f32x4*)&orow[c + 4] = r1;
  }
}

// ---------------------------------------------------------------------------
extern "C" void kernel_launch(void* const* d_in, const int* in_sizes, int n_in,
                              void* d_out, int out_size, void* d_ws, size_t ws_size,
                              hipStream_t stream) {
  const float* x  = (const float*)d_in[0];   // fp32 inputs per reference
  const float* Wq = (const float*)d_in[1];
  const float* Wk = (const float*)d_in[2];
  const float* Wv = (const float*)d_in[3];
  float* out = (float*)d_out;                // fp32 output

  f16*  wt  = (f16*)d_ws;                             // 3*H*C fp16
  f16*  qf  = wt + (size_t)3 * H * C;                 // M*H fp16
  f16*  kf  = qf + (size_t)M * H;                     // M*H fp16
  f16*  vf  = kf + (size_t)M * H;                     // M*H fp16 [b][h][t]
  f16*  oS  = vf + (size_t)M * H;                     // 256*64*128 fp16
  float* MLs = (float*)(oS + (size_t)256 * 64 * 128); // 256*2*64*2 f32

  kwt<<<dim3(C / 32, H / 32, 3), 256, 0, stream>>>(Wq, Wk, Wv, wt);
  proj_kernel<<<dim3(M / 64, 3), 256, 0, stream>>>(x, wt, qf, kf, vf);
  attn_kernel<<<512, 256, 0, stream>>>(qf, kf, vf, out, oS, MLs);
  combine_kernel<<<256, 256, 0, stream>>>(out, oS, MLs);
}

// Round 9
// 64.383 us; speedup vs baseline: 1.9160x; 1.0487x over previous
//
#include <hip/hip_runtime.h>

typedef __bf16 bf16;
typedef _Float16 f16;
typedef f16 f16x4 __attribute__((ext_vector_type(4)));
typedef f16 f16x8 __attribute__((ext_vector_type(8)));
typedef float f32x4 __attribute__((ext_vector_type(4)));

#define MFMA_FP(a, b, c) __builtin_amdgcn_mfma_f32_16x16x32_f16((a), (b), (c), 0, 0, 0)

static constexpr int Bn = 8, T = 2048, C = 1024, H = 128;
static constexpr int M = Bn * T; // 16384

// direct global->LDS, 16B per lane (lds dest is wave-uniform base + lane*16)
__device__ __forceinline__ void gll16(const void* g, void* l) {
  __builtin_amdgcn_global_load_lds(
      (const __attribute__((address_space(1))) unsigned int*)g,
      (__attribute__((address_space(3))) unsigned int*)l, 16, 0, 0);
}

// ---------------------------------------------------------------------------
// Kernel 0: transpose  W[C][H] fp32 -> wt [3][H][C] fp16 (single plane)
// ---------------------------------------------------------------------------
__global__ __launch_bounds__(256) void kwt(const float* __restrict__ Wq,
                                           const float* __restrict__ Wk,
                                           const float* __restrict__ Wv,
                                           f16* __restrict__ wt) {
  __shared__ float tl[32][33];
  const int w = blockIdx.z;
  const float* src = (w == 0) ? Wq : (w == 1) ? Wk : Wv;
  f16* dh = wt + (size_t)w * H * C;
  const int k0 = blockIdx.x * 32, n0 = blockIdx.y * 32;
  const int tx = threadIdx.x & 31, ty = threadIdx.x >> 5; // 32 x 8
  for (int i = ty; i < 32; i += 8) tl[i][tx] = src[(size_t)(k0 + i) * H + n0 + tx];
  __syncthreads();
  for (int i = ty; i < 32; i += 8)
    dh[(size_t)(n0 + i) * C + k0 + tx] = (f16)tl[tx][i];
}

// ---------------------------------------------------------------------------
// Kernel 1: QKV projection, single-term fp16 math, f32 accumulate.
// grid (M/64, 3) = 768 blocks (3/CU).  256 thr = 4 waves (2x2).
// Tile 64m x 128n, BK=64.  Staging via global_load_lds width-16:
//   As = x tile fp32 [64][64] (16KB), cvt->fp16 at frag read;
//   Bs = wt tile fp16 [128][64] (16KB).
// LDS dest linear; SOURCE chunk pre-XOR'd (logical = phys ^ (row&7)) so
// frag reads with phys = logical ^ (row&7) are the verified conflict pattern.
// y==0 -> q fp16 [t][h]; y==1 -> k fp16; y==2 -> v fp16 transposed [b][h][t].
// ---------------------------------------------------------------------------
__global__ __launch_bounds__(256) void proj_kernel(const float* __restrict__ x,
                                                   const f16* __restrict__ wt,
                                                   f16* __restrict__ qo,
                                                   f16* __restrict__ ko,
                                                   f16* __restrict__ vt) {
  __shared__ __align__(16) float As[64 * 64];   // [m][k] f32, swizzled, 16KB
  __shared__ __align__(16) f16  Bs[128 * 64];   // [n][k] f16, swizzled, 16KB
  const int tid = threadIdx.x;
  const int lane = tid & 63, g = lane >> 4, r16 = lane & 15;
  const int wave = tid >> 6, wr = wave >> 1, wc = wave & 1;
  const int m0 = blockIdx.x * 64;
  const int which = blockIdx.y;
  const f16* wh = wt + (size_t)which * H * C;

  // A: 64 rows x 256B = 16 units of 1KB (4 rows each); wave stages 4 units.
  //   lane l in unit u: LDS chunk = l (linear); row = u*4 + (l>>4);
  //   source f32 col-chunk = (l&15) ^ (row&7)  (16B = 4 f32 per chunk).
  // B: 128 rows x 128B = 16 units (8 rows each); source chunk = (l&7)^(row&7).
  int asrc[4], bsrc[4];      // source element offsets (excl. k0)
  int aldu[4], bldu[4];      // LDS unit base (element index), wave-uniform
#pragma unroll
  for (int i = 0; i < 4; ++i) {
    const int u = wave * 4 + i;
    const int ra = u * 4 + (lane >> 4);
    asrc[i] = (m0 + ra) * C + (((lane & 15) ^ (ra & 7)) << 2);
    aldu[i] = u * 256;                      // 256 f32 per unit
    const int rb = u * 8 + (lane >> 3);
    bsrc[i] = rb * C + (((lane & 7) ^ (rb & 7)) << 3);
    bldu[i] = u * 512;                      // 512 f16 per unit
  }

  f32x4 acc[2][4] = {};

#define ISSUE(K0)                                                  \
  _Pragma("unroll")                                                \
  for (int i = 0; i < 4; ++i) {                                    \
    gll16(&x[asrc[i] + (K0)], &As[aldu[i]]);                       \
    gll16(&wh[bsrc[i] + (K0)], &Bs[bldu[i]]);                      \
  }

  ISSUE(0);
  for (int k0 = 0; k0 < C; k0 += 64) {
    __syncthreads();   // vmcnt drained before barrier -> tile ready
#pragma unroll
    for (int kb = 0; kb < 2; ++kb) {
      f16x8 af[2], bf[4];
#pragma unroll
      for (int mt = 0; mt < 2; ++mt) {
        const int r = wr * 32 + mt * 16 + r16;
        const int s = r & 7;
        const f32x4 a0 = *(const f32x4*)&As[r * 64 + (((kb * 8 + g * 2) ^ s) << 2)];
        const f32x4 a1 = *(const f32x4*)&As[r * 64 + (((kb * 8 + g * 2 + 1) ^ s) << 2)];
#pragma unroll
        for (int j = 0; j < 4; ++j) { af[mt][j] = (f16)a0[j]; af[mt][4 + j] = (f16)a1[j]; }
      }
#pragma unroll
      for (int nt = 0; nt < 4; ++nt) {
        const int r = wc * 64 + nt * 16 + r16;
        const int phys = (kb * 4 + g) ^ (r & 7);
        bf[nt] = *(const f16x8*)&Bs[r * 64 + phys * 8];
      }
#pragma unroll
      for (int mt = 0; mt < 2; ++mt)
#pragma unroll
        for (int nt = 0; nt < 4; ++nt)
          acc[mt][nt] = MFMA_FP(af[mt], bf[nt], acc[mt][nt]);
    }
    __syncthreads();   // all reads done before next tile overwrites
    if (k0 + 64 < C) ISSUE(k0 + 64);
  }
#undef ISSUE

  // epilogue.  C/D frag: col = lane&15, row = (lane>>4)*4 + reg  [m89]
  if (which < 2) {
    f16* dst = which ? ko : qo;
#pragma unroll
    for (int mt = 0; mt < 2; ++mt)
#pragma unroll
      for (int nt = 0; nt < 4; ++nt) {
        const int mb = m0 + wr * 32 + mt * 16 + g * 4;
        const int col = wc * 64 + nt * 16 + r16;
#pragma unroll
        for (int r = 0; r < 4; ++r)
          dst[(size_t)(mb + r) * H + col] = (f16)acc[mt][nt][r];
      }
  } else {
    const int b = m0 >> 11;
    const int tb0 = m0 & 2047;
    f16* vbase = vt + (size_t)b * H * T;
#pragma unroll
    for (int mt = 0; mt < 2; ++mt)
#pragma unroll
      for (int nt = 0; nt < 4; ++nt) {
        const int tib = tb0 + wr * 32 + mt * 16 + g * 4;
        const int h = wc * 64 + nt * 16 + r16;
        f16x4 pk;
#pragma unroll
        for (int r = 0; r < 4; ++r) pk[r] = (f16)acc[mt][nt][r];
        *(f16x4*)&vbase[(size_t)h * T + tib] = pk;
      }
  }
}

// ---------------------------------------------------------------------------
// Kernel 2: causal flash attention, fp16, block-level s-parity split.
// 512 blocks: b = bb&7 (XCD-pinned), qt = 31-(bb>>4) (heavy first, LPT),
// par = (bb>>3)&1.  Block = 64 q-rows (4 waves x 16), processes s-tiles
// j = par, par+2, ... <= qt.  K [64][128] + V^T [128][64] fp16 double-buffered
// in LDS (XOR chunk-swizzle), ONE barrier per tile.  1-term fp16 QK^T; P fp16.
// par0 writes normalized O (f32) to d_out; par1 to scratch; combine merges.
// ---------------------------------------------------------------------------
__global__ __launch_bounds__(256, 2) void attn_kernel(const f16* __restrict__ qp,
                                                      const f16* __restrict__ kp,
                                                      const f16* __restrict__ vp,
                                                      float* __restrict__ out,
                                                      f16* __restrict__ oS,
                                                      float* __restrict__ MLs) {
  __shared__ __align__(16) f16 KS[2][64 * 128];   // [s][h], chunk-swizzled
  __shared__ __align__(16) f16 VS[2][128 * 64];   // [h][s], chunk-swizzled
  __shared__ __align__(16) f16 Pl[4][16][72];     // per-wave P [q][s], padded

  const int tid = threadIdx.x, lane = tid & 63, wave = tid >> 6;
  const int g = lane >> 4, q15 = lane & 15;
  const int x7 = q15 & 7;
  const int bb = blockIdx.x;
  const int b = bb & 7;                 // block->XCD round-robin: pins batch L2
  const int t2 = bb >> 3;               // 0..63
  const int qt = 31 - (t2 >> 1);        // heavy tasks dispatch first (LPT)
  const int par = t2 & 1;
  const int q0 = qt * 64;
  const int qrow = q0 + wave * 16 + q15;
  const int task = b * 32 + qt;

  const f16* qb = qp + (size_t)b * T * H;
  const f16* kb = kp + (size_t)b * T * H;
  const f16* vb = vp + (size_t)b * H * T;

  int koff[4], voff[4], lo[4];
#pragma unroll
  for (int i = 0; i < 4; ++i) {
    const int u = wave * 4 + i;
    const int rK = u * 4 + (lane >> 4);
    koff[i] = rK * H + (((lane & 15) ^ (rK & 7)) << 3);
    const int hV = u * 8 + (lane >> 3);
    voff[i] = hV * T + (((lane & 7) ^ (hV & 7)) << 3);
    lo[i] = u * 512 + lane * 8;
  }

  const int n = (qt >= par) ? ((qt - par) >> 1) + 1 : 0;   // my tile count

  f16x8 qf[4];
#pragma unroll
  for (int k4 = 0; k4 < 4; ++k4)
    qf[k4] = *(const f16x8*)&qb[(size_t)qrow * H + k4 * 32 + g * 8];

  f32x4 o[8] = {};
  float mrun = -1e30f, lrun = 0.f;

  f16x8 rk[4], rv[4];
#define LOADT(S0)                                                   \
  _Pragma("unroll")                                                 \
  for (int i = 0; i < 4; ++i) {                                     \
    rk[i] = *(const f16x8*)&kb[(size_t)(S0) * H + koff[i]];         \
    rv[i] = *(const f16x8*)&vb[(size_t)(S0) + voff[i]];             \
  }
#define WRITET(BUF)                                                 \
  _Pragma("unroll")                                                 \
  for (int i = 0; i < 4; ++i) {                                     \
    *(f16x8*)&KS[BUF][lo[i]] = rk[i];                               \
    *(f16x8*)&VS[BUF][lo[i]] = rv[i];                               \
  }

  if (n > 0) {
    LOADT(par * 64);
    WRITET(0);
    if (n > 1) LOADT(par * 64 + 128);

    for (int k = 0; k < n; ++k) {
      const int s0 = par * 64 + k * 128;
      const int cur = k & 1;
      __syncthreads();  // WRITET(cur) by all waves complete

      f32x4 sacc[4] = {};
#pragma unroll
      for (int mt = 0; mt < 4; ++mt) {
        const int row = mt * 16 + q15;
#pragma unroll
        for (int k4 = 0; k4 < 4; ++k4) {
          const int pch = (k4 * 4 + g) ^ (row & 7);
          const f16x8 kf = *(const f16x8*)&KS[cur][row * 128 + pch * 8];
          sacc[mt] = MFMA_FP(kf, qf[k4], sacc[mt]);
        }
      }
      if (k == n - 1) {
#pragma unroll
        for (int mt = 0; mt < 4; ++mt)
#pragma unroll
          for (int r = 0; r < 4; ++r)
            if (s0 + mt * 16 + g * 4 + r > qrow) sacc[mt][r] = -1e30f;
      }
      float tmax = -1e30f;
#pragma unroll
      for (int mt = 0; mt < 4; ++mt)
#pragma unroll
        for (int r = 0; r < 4; ++r) tmax = fmaxf(tmax, sacc[mt][r]);
      tmax = fmaxf(tmax, __shfl_xor(tmax, 16));
      tmax = fmaxf(tmax, __shfl_xor(tmax, 32));
      const float mnew = fmaxf(mrun, tmax);
      const float alpha = __expf(mrun - mnew);
      float lt = 0.f;
#pragma unroll
      for (int mt = 0; mt < 4; ++mt) {
        f16x4 pk;
#pragma unroll
        for (int r = 0; r < 4; ++r) {
          const float p = __expf(sacc[mt][r] - mnew);
          lt += p;
          pk[r] = (f16)p;
        }
        *(f16x4*)&Pl[wave][q15][mt * 16 + g * 4] = pk;
      }
      lt += __shfl_xor(lt, 16);
      lt += __shfl_xor(lt, 32);
      lrun = lrun * alpha + lt;
      mrun = mnew;
#pragma unroll
      for (int i = 0; i < 8; ++i) o[i] *= alpha;
      const f16x8 pf0 = *(const f16x8*)&Pl[wave][q15][g * 8];
      const f16x8 pf1 = *(const f16x8*)&Pl[wave][q15][32 + g * 8];
#pragma unroll
      for (int mt = 0; mt < 8; ++mt) {
        const int h = mt * 16 + q15;
        const f16x8 vf0 = *(const f16x8*)&VS[cur][h * 64 + ((g ^ x7) << 3)];
        o[mt] = MFMA_FP(vf0, pf0, o[mt]);
        const f16x8 vf1 = *(const f16x8*)&VS[cur][h * 64 + (((4 + g) ^ x7) << 3)];
        o[mt] = MFMA_FP(vf1, pf1, o[mt]);
      }

      if (k + 1 < n) {
        WRITET(cur ^ 1);
        if (k + 2 < n) LOADT(par * 64 + (k + 2) * 128);
      }
    }
  }
#undef LOADT
#undef WRITET

  const float inv = (lrun > 0.f) ? 1.0f / lrun : 0.f;
  if (lane < 16) {
    MLs[((size_t)(task * 2 + par) * 64 + wave * 16 + lane) * 2 + 0] = mrun;
    MLs[((size_t)(task * 2 + par) * 64 + wave * 16 + lane) * 2 + 1] = lrun;
  }
  if (par == 0) {
    float* ob = out + ((size_t)b * T + qrow) * H;
#pragma unroll
    for (int mt = 0; mt < 8; ++mt) {
      f32x4 pk;
#pragma unroll
      for (int r = 0; r < 4; ++r) pk[r] = o[mt][r] * inv;
      *(f32x4*)&ob[mt * 16 + g * 4] = pk;
    }
  } else {
    f16* sb = oS + ((size_t)task * 64 + wave * 16 + q15) * 128;
#pragma unroll
    for (int mt = 0; mt < 8; ++mt) {
      f16x4 pk;
#pragma unroll
      for (int r = 0; r < 4; ++r) pk[r] = (f16)(o[mt][r] * inv);
      *(f16x4*)&sb[mt * 16 + g * 4] = pk;
    }
  }
}

// ---------------------------------------------------------------------------
// Kernel 3: combine the two parity partials per task (flash merge), in-place.
// ---------------------------------------------------------------------------
__global__ __launch_bounds__(256) void combine_kernel(float* __restrict__ out,
                                                      const f16* __restrict__ oS,
                                                      const float* __restrict__ MLs) {
  const int task = blockIdx.x;           // b*32 + qt
  const int b = task >> 5, qt = task & 31;
  const int tid = threadIdx.x;
  const int row = tid >> 2;
  const int cb = (tid & 3) * 32;
  const float m0 = MLs[((size_t)(task * 2 + 0) * 64 + row) * 2 + 0];
  const float l0 = MLs[((size_t)(task * 2 + 0) * 64 + row) * 2 + 1];
  const float m1 = MLs[((size_t)(task * 2 + 1) * 64 + row) * 2 + 0];
  const float l1 = MLs[((size_t)(task * 2 + 1) * 64 + row) * 2 + 1];
  const float Mg = fmaxf(m0, m1);
  const float w0 = l0 * __expf(m0 - Mg);
  const float w1 = l1 * __expf(m1 - Mg);
  const float inv = 1.0f / (w0 + w1);
  float* orow = out + ((size_t)b * T + qt * 64 + row) * H + cb;
  const f16* srow = oS + ((size_t)task * 64 + row) * 128 + cb;
#pragma unroll
  for (int c = 0; c < 32; c += 8) {
    const f16x8 o1 = *(const f16x8*)&srow[c];
    f32x4 a0 = *(const f32x4*)&orow[c];
    f32x4 a1 = *(const f32x4*)&orow[c + 4];
    f32x4 r0, r1;
#pragma unroll
    for (int r = 0; r < 4; ++r) {
      r0[r] = (w0 * a0[r] + w1 * (float)o1[r]) * inv;
      r1[r] = (w0 * a1[r] + w1 * (float)o1[4 + r]) * inv;
    }
    *(f32x4*)&orow[c] = r0;
    *(f32x4*)&orow[c + 4] = r1;
  }
}

// ---------------------------------------------------------------------------
extern "C" void kernel_launch(void* const* d_in, const int* in_sizes, int n_in,
                              void* d_out, int out_size, void* d_ws, size_t ws_size,
                              hipStream_t stream) {
  const float* x  = (const float*)d_in[0];   // fp32 inputs per reference
  const float* Wq = (const float*)d_in[1];
  const float* Wk = (const float*)d_in[2];
  const float* Wv = (const float*)d_in[3];
  float* out = (float*)d_out;                // fp32 output

  f16*  wt  = (f16*)d_ws;                             // 3*H*C fp16
  f16*  qf  = wt + (size_t)3 * H * C;                 // M*H fp16
  f16*  kf  = qf + (size_t)M * H;                     // M*H fp16
  f16*  vf  = kf + (size_t)M * H;                     // M*H fp16 [b][h][t]
  f16*  oS  = vf + (size_t)M * H;                     // 256*64*128 fp16
  float* MLs = (float*)(oS + (size_t)256 * 64 * 128); // 256*2*64*2 f32

  kwt<<<dim3(C / 32, H / 32, 3), 256, 0, stream>>>(Wq, Wk, Wv, wt);
  proj_kernel<<<dim3(M / 64, 3), 256, 0, stream>>>(x, wt, qf, kf, vf);
  attn_kernel<<<512, 256, 0, stream>>>(qf, kf, vf, out, oS, MLs);
  combine_kernel<<<256, 256, 0, stream>>>(out, oS, MLs);
}